// Round 4
// baseline (320.439 us; speedup 1.0000x reference)
//
#include <hip/hip_runtime.h>
#include <math.h>

// DigitCaps dynamic routing, f16-dot2 with fp32 accumulate. u never materialized;
// logits linear in v (b2 = u.(v0+v1)) so no logit buffer.
// R4: batch-block x2 (halves W LDS-broadcast traffic, the R3 bottleneck),
// pre-packed transposed x_h (conflict-free sequential b128 LDS reads),
// designated-thread softmax-denominator (cuts exchange LDS 5x),
// 4-accumulator reduces (breaks the serial-chain latency).

namespace {
constexpr int B_  = 128;
constexpr int N_  = 4608;
constexpr int C_  = 10;
constexpr int L_  = 16;
constexpr int BCL = B_ * C_ * L_;      // 20480
constexpr int RED_G = 16;
}

typedef _Float16 h2 __attribute__((ext_vector_type(2)));
union U32H2 { unsigned int u; h2 h; };
__device__ inline h2 uph(unsigned int v) { U32H2 t; t.u = v; return t.h; }
__device__ inline unsigned int packh2(float a, float b) {
    h2 h; h[0] = (_Float16)a; h[1] = (_Float16)b;
    U32H2 t; t.h = h; return t.u;
}

#if defined(__has_builtin)
#if __has_builtin(__builtin_amdgcn_fdot2)
#define HAVE_FDOT2 1
#endif
#endif
__device__ inline float fdot2(h2 a, h2 b, float c) {
#ifdef HAVE_FDOT2
    return __builtin_amdgcn_fdot2(a, b, c, false);
#else
    return c + (float)a[0] * (float)b[0] + (float)a[1] * (float)b[1];
#endif
}

// W[N][8][160] f32 -> Wh[N][jp=4][160] u32 = half2(j=2jp, j=2jp+1)
__global__ __launch_bounds__(256)
void conv_w(const float* __restrict__ W, unsigned int* __restrict__ Wh) {
    const int t  = blockIdx.x * 256 + threadIdx.x;
    const int cl = t % 160;
    const int r  = t / 160;
    const int n  = r >> 2, jp = r & 3;
    const float* p = W + ((size_t)n * 8 + jp * 2) * 160 + cl;
    Wh[t] = packh2(p[0], p[160]);
}

// x[B][N][8] f32 -> Xh[N][B][4] u32 (transposed: batch-fast for pass staging)
__global__ __launch_bounds__(256)
void conv_x(const float* __restrict__ x, unsigned int* __restrict__ Xh) {
    const int t = blockIdx.x * 256 + threadIdx.x;   // n*128 + b, b fast
    const int b = t & 127;
    const int n = t >> 7;
    const float4 f0 = *(const float4*)(x + ((size_t)b * N_ + n) * 8);
    const float4 f1 = *(const float4*)(x + ((size_t)b * N_ + n) * 8 + 4);
    uint4 o;
    o.x = packh2(f0.x, f0.y); o.y = packh2(f0.z, f0.w);
    o.z = packh2(f1.x, f1.y); o.w = packh2(f1.z, f1.w);
    ((uint4*)Xh)[t] = o;
}

// MODE 0: iter0 uniform coupling (1/10 in reduce scale)
// MODE 1: logits t = u.v0      MODE 2: logits t = u.(v0+v1)
// Block: 640 thr = 10 waves (one per c); lane bl handles batches bl and bl+64.
template<int MODE, int NCH>
__global__ __launch_bounds__(640, 5)
void pass_kernel(const unsigned int* __restrict__ Xh,   // [N][128][4] half2
                 const unsigned int* __restrict__ Wh,   // [N][4][160] half2
                 const float* __restrict__ va,
                 const float* __restrict__ vb,
                 float* __restrict__ partials)          // [NCH][B][C][L]
{
    constexpr int TILE = N_ / NCH;
    __shared__ unsigned int w_lds[TILE * 640];
    __shared__ unsigned int x_lds[TILE * 512];
    __shared__ float t_et[2][C_][130];   // exp(t), transposed [c][b]
    __shared__ float es_l[2][130];       // softmax denominators per b

    const int tid = threadIdx.x;
    const int c   = tid >> 6;
    const int bl  = tid & 63;
    const int n0  = blockIdx.x * TILE;

    {   // W slab, coalesced uint4
        const uint4* s = (const uint4*)(Wh + (size_t)n0 * 640);
        uint4* d = (uint4*)w_lds;
        for (int i = tid; i < TILE * 160; i += 640) d[i] = s[i];
    }
    {   // x slab (already packed+transposed), coalesced uint4
        const uint4* s = (const uint4*)(Xh + (size_t)n0 * 512);
        uint4* d = (uint4*)x_lds;
        for (int i = tid; i < TILE * 128; i += 640) d[i] = s[i];
    }

    float vr0[L_], vr1[L_];
    if (MODE >= 1) {
        #pragma unroll
        for (int l = 0; l < L_; ++l) {
            vr0[l] = va[((size_t)bl * C_ + c) * L_ + l];
            vr1[l] = va[((size_t)(bl + 64) * C_ + c) * L_ + l];
        }
        if (MODE == 2) {
            #pragma unroll
            for (int l = 0; l < L_; ++l) {
                vr0[l] += vb[((size_t)bl * C_ + c) * L_ + l];
                vr1[l] += vb[((size_t)(bl + 64) * C_ + c) * L_ + l];
            }
        }
    }
    __syncthreads();

    float s0[L_], s1[L_];
    #pragma unroll
    for (int l = 0; l < L_; ++l) { s0[l] = 0.f; s1[l] = 0.f; }

    const int coff = __builtin_amdgcn_readfirstlane(c * L_);

    for (int nn = 0; nn < TILE; ++nn) {
        // x: lane-sequential 16B-stride b128 -> conflict-free
        const uint4 xq0 = ((const uint4*)x_lds)[nn * 128 + bl];
        const uint4 xq1 = ((const uint4*)x_lds)[nn * 128 + 64 + bl];
        const unsigned int xa0[4] = {xq0.x, xq0.y, xq0.z, xq0.w};
        const unsigned int xa1[4] = {xq1.x, xq1.y, xq1.z, xq1.w};
        const unsigned int* wb = w_lds + nn * 640 + coff;

        float u0[L_], u1[L_];
        #pragma unroll
        for (int l = 0; l < L_; ++l) { u0[l] = 0.f; u1[l] = 0.f; }
        #pragma unroll
        for (int jp = 0; jp < 4; ++jp) {
            const h2 xh0 = uph(xa0[jp]);
            const h2 xh1 = uph(xa1[jp]);
            #pragma unroll
            for (int q = 0; q < 4; ++q) {
                const uint4 w4 = *(const uint4*)(wb + jp * 160 + q * 4);
                const unsigned int wa[4] = {w4.x, w4.y, w4.z, w4.w};
                #pragma unroll
                for (int e = 0; e < 4; ++e) {
                    const h2 wh = uph(wa[e]);
                    u0[4 * q + e] = fdot2(xh0, wh, u0[4 * q + e]);
                    u1[4 * q + e] = fdot2(xh1, wh, u1[4 * q + e]);
                }
            }
        }

        if (MODE == 0) {
            #pragma unroll
            for (int l = 0; l < L_; ++l) { s0[l] += u0[l]; s1[l] += u1[l]; }
        } else {
            float t0 = 0.f, t1 = 0.f;
            #pragma unroll
            for (int l = 0; l < L_; ++l) {
                t0 = fmaf(u0[l], vr0[l], t0);
                t1 = fmaf(u1[l], vr1[l], t1);
            }
            const float e0 = __expf(t0);      // |t| small, no max-shift needed
            const float e1 = __expf(t1);
            const int pb = nn & 1;            // parity double-buffer: 2 barriers/iter
            t_et[pb][c][bl]      = e0;
            t_et[pb][c][bl + 64] = e1;
            __syncthreads();
            if (tid < 128) {                  // designated denominator sum
                float es = 0.f;
                #pragma unroll
                for (int cc = 0; cc < C_; ++cc) es += t_et[pb][cc][tid];
                es_l[pb][tid] = es;
            }
            __syncthreads();
            const float w0 = e0 * __builtin_amdgcn_rcpf(es_l[pb][bl]);
            const float w1 = e1 * __builtin_amdgcn_rcpf(es_l[pb][bl + 64]);
            #pragma unroll
            for (int l = 0; l < L_; ++l) {
                s0[l] = fmaf(w0, u0[l], s0[l]);
                s1[l] = fmaf(w1, u1[l], s1[l]);
            }
        }
    }

    float* p0 = partials + (((size_t)blockIdx.x * B_ + bl) * C_ + c) * L_;
    float* p1 = partials + (((size_t)blockIdx.x * B_ + bl + 64) * C_ + c) * L_;
    #pragma unroll
    for (int q = 0; q < 4; ++q) {
        *(float4*)(p0 + 4 * q) = make_float4(s0[4*q], s0[4*q+1], s0[4*q+2], s0[4*q+3]);
        *(float4*)(p1 + 4 * q) = make_float4(s1[4*q], s1[4*q+1], s1[4*q+2], s1[4*q+3]);
    }
}

// Stage A: NCH chunks -> 16 groups; 4 independent accumulators (chain depth K/4)
template<int NCH>
__global__ __launch_bounds__(256)
void reduce_a(const float* __restrict__ p, float* __restrict__ p2) {
    const int t   = blockIdx.x * 256 + threadIdx.x;   // < RED_G*BCL
    const int idx = t % BCL;
    const int g   = t / BCL;
    constexpr int K = NCH / RED_G;
    const float* base = p + (size_t)g * K * BCL + idx;
    float a0 = 0.f, a1 = 0.f, a2 = 0.f, a3 = 0.f;
    #pragma unroll
    for (int k = 0; k < K; k += 4) {
        a0 += base[(size_t)(k + 0) * BCL];
        a1 += base[(size_t)(k + 1) * BCL];
        a2 += base[(size_t)(k + 2) * BCL];
        a3 += base[(size_t)(k + 3) * BCL];
    }
    p2[t] = (a0 + a1) + (a2 + a3);
}

// Stage B: sum 16 groups, bias, squash (16-lane shuffle tree for ||s||^2)
__global__ __launch_bounds__(256)
void reduce_b(const float* __restrict__ p2, const float* __restrict__ biases,
              float* __restrict__ vout, float scale) {
    const int idx = blockIdx.x * 256 + threadIdx.x;   // < BCL
    float a0 = 0.f, a1 = 0.f, a2 = 0.f, a3 = 0.f;
    #pragma unroll
    for (int g = 0; g < RED_G; g += 4) {
        a0 += p2[(size_t)(g + 0) * BCL + idx];
        a1 += p2[(size_t)(g + 1) * BCL + idx];
        a2 += p2[(size_t)(g + 2) * BCL + idx];
        a3 += p2[(size_t)(g + 3) * BCL + idx];
    }
    const float s = ((a0 + a1) + (a2 + a3)) * scale + biases[idx % 160];
    float n2 = s * s;
    #pragma unroll
    for (int o = 8; o; o >>= 1) n2 += __shfl_xor(n2, o, 16);
    const float n = sqrtf(n2);
    const float f = n2 / ((1.f + n2) * (n + 1e-7f));
    vout[idx] = f * s;
}

template<int NCH>
static void run_all(const float* x, const float* W, const float* biases,
                    float* out, float* ws, hipStream_t stream) {
    unsigned int* Wh = (unsigned int*)ws;                 // N*640 u32   = 11.8 MB
    unsigned int* Xh = Wh + (size_t)N_ * 640;             // N*512 u32   =  9.4 MB
    float* partials  = (float*)(Xh + (size_t)N_ * 512);   // NCH*BCL f32
    float* p2        = partials + (size_t)NCH * BCL;      // 16*BCL
    float* v0        = p2 + (size_t)RED_G * BCL;
    float* v1        = v0 + BCL;

    conv_w<<<(N_ * 640) / 256, 256, 0, stream>>>(W, Wh);
    conv_x<<<(N_ * 128) / 256, 256, 0, stream>>>(x, Xh);

    const dim3 pg(NCH), pb(640);
    const dim3 ag((RED_G * BCL) / 256), bg(BCL / 256);

    pass_kernel<0, NCH><<<pg, pb, 0, stream>>>(Xh, Wh, nullptr, nullptr, partials);
    reduce_a<NCH><<<ag, 256, 0, stream>>>(partials, p2);
    reduce_b<<<bg, 256, 0, stream>>>(p2, biases, v0, 0.1f);

    pass_kernel<1, NCH><<<pg, pb, 0, stream>>>(Xh, Wh, v0, nullptr, partials);
    reduce_a<NCH><<<ag, 256, 0, stream>>>(partials, p2);
    reduce_b<<<bg, 256, 0, stream>>>(p2, biases, v1, 1.0f);

    pass_kernel<2, NCH><<<pg, pb, 0, stream>>>(Xh, Wh, v0, v1, partials);
    reduce_a<NCH><<<ag, 256, 0, stream>>>(partials, p2);
    reduce_b<<<bg, 256, 0, stream>>>(p2, biases, out, 1.0f);
}

extern "C" void kernel_launch(void* const* d_in, const int* in_sizes, int n_in,
                              void* d_out, int out_size, void* d_ws, size_t ws_size,
                              hipStream_t stream) {
    const float* x      = (const float*)d_in[0];
    const float* W      = (const float*)d_in[1];
    const float* biases = (const float*)d_in[2];
    // 512-chunk path needs 64.7 MB of ws; fall back to 256 (43.7 MB) if tight.
    if (ws_size >= (size_t)65000000)
        run_all<512>(x, W, biases, (float*)d_out, (float*)d_ws, stream);
    else
        run_all<256>(x, W, biases, (float*)d_out, (float*)d_ws, stream);
}

// Round 5
// 252.703 us; speedup vs baseline: 1.2680x; 1.2680x over previous
//
#include <hip/hip_runtime.h>
#include <math.h>

// DigitCaps dynamic routing, f16-dot2 with fp32 accumulate. u never materialized;
// logits linear in v (b2 = u.(v0+v1)) so no logit buffer.
// R5: R4 structure (2 batches/lane -> half the W LDS-broadcast instrs) but with
// __launch_bounds__(640,3): R4's (640,5) forced a 102-VGPR cap and the compiler
// spilled ~80 floats/lane to scratch (VGPR=48, +27MB/pass scratch stores,
// VALUBusy 17%). 170-VGPR budget fits the ~130 live values. Single-buffered
// softmax exchange (barrier pair already orders it).

namespace {
constexpr int B_   = 128;
constexpr int N_   = 4608;
constexpr int C_   = 10;
constexpr int L_   = 16;
constexpr int BCL  = B_ * C_ * L_;     // 20480
constexpr int NCH  = 512;              // blocks; 2 clean rounds over 256 CUs
constexpr int TILE = N_ / NCH;         // 9
constexpr int RED_G = 16;
}

typedef _Float16 h2 __attribute__((ext_vector_type(2)));
union U32H2 { unsigned int u; h2 h; };
__device__ inline h2 uph(unsigned int v) { U32H2 t; t.u = v; return t.h; }
__device__ inline unsigned int packh2(float a, float b) {
    h2 h; h[0] = (_Float16)a; h[1] = (_Float16)b;
    U32H2 t; t.h = h; return t.u;
}

#if defined(__has_builtin)
#if __has_builtin(__builtin_amdgcn_fdot2)
#define HAVE_FDOT2 1
#endif
#endif
__device__ inline float fdot2(h2 a, h2 b, float c) {
#ifdef HAVE_FDOT2
    return __builtin_amdgcn_fdot2(a, b, c, false);
#else
    return c + (float)a[0] * (float)b[0] + (float)a[1] * (float)b[1];
#endif
}

// W[N][8][160] f32 -> Wh[N][jp=4][160] u32 = half2(j=2jp, j=2jp+1)
__global__ __launch_bounds__(256)
void conv_w(const float* __restrict__ W, unsigned int* __restrict__ Wh) {
    const int t  = blockIdx.x * 256 + threadIdx.x;
    const int cl = t % 160;
    const int r  = t / 160;
    const int n  = r >> 2, jp = r & 3;
    const float* p = W + ((size_t)n * 8 + jp * 2) * 160 + cl;
    Wh[t] = packh2(p[0], p[160]);
}

// x[B][N][8] f32 -> Xh[N][B][4] u32 (transposed: batch-fast for pass staging)
__global__ __launch_bounds__(256)
void conv_x(const float* __restrict__ x, unsigned int* __restrict__ Xh) {
    const int t = blockIdx.x * 256 + threadIdx.x;   // n*128 + b
    const int b = t & 127;
    const int n = t >> 7;
    const float4 f0 = *(const float4*)(x + ((size_t)b * N_ + n) * 8);
    const float4 f1 = *(const float4*)(x + ((size_t)b * N_ + n) * 8 + 4);
    uint4 o;
    o.x = packh2(f0.x, f0.y); o.y = packh2(f0.z, f0.w);
    o.z = packh2(f1.x, f1.y); o.w = packh2(f1.z, f1.w);
    ((uint4*)Xh)[t] = o;
}

__device__ inline void store16(float* p, const float* s) {
    #pragma unroll
    for (int q = 0; q < 4; ++q)
        *(float4*)(p + 4 * q) = make_float4(s[4*q], s[4*q+1], s[4*q+2], s[4*q+3]);
}
__device__ inline void store16(_Float16* p, const float* s) {
    uint4 o0, o1;
    o0.x = packh2(s[0],  s[1]);  o0.y = packh2(s[2],  s[3]);
    o0.z = packh2(s[4],  s[5]);  o0.w = packh2(s[6],  s[7]);
    o1.x = packh2(s[8],  s[9]);  o1.y = packh2(s[10], s[11]);
    o1.z = packh2(s[12], s[13]); o1.w = packh2(s[14], s[15]);
    *(uint4*)p = o0;
    *(uint4*)(p + 8) = o1;
}

// MODE 0: iter0 uniform coupling (1/10 in reduce scale)
// MODE 1: logits t = u.v0      MODE 2: logits t = u.(v0+v1)
// Block: 640 thr = 10 waves (one per c); lane bl handles batches bl and bl+64.
template<int MODE, typename PT>
__global__ __launch_bounds__(640, 3)
void pass_kernel(const unsigned int* __restrict__ Xh,   // [N][128][4] half2
                 const unsigned int* __restrict__ Wh,   // [N][4][160] half2
                 const float* __restrict__ va,
                 const float* __restrict__ vb,
                 PT* __restrict__ partials)             // [NCH][B][C][L]
{
    __shared__ unsigned int w_lds[TILE * 640];   // 23040 B
    __shared__ unsigned int x_lds[TILE * 512];   // 18432 B
    __shared__ float t_et[C_][128];              //  5120 B  exp(t), [c][b]
    __shared__ float es_l[128];                  //   512 B  softmax denominators

    const int tid = threadIdx.x;
    const int c   = tid >> 6;
    const int bl  = tid & 63;
    const int n0  = blockIdx.x * TILE;

    {   // W slab, coalesced uint4
        const uint4* s = (const uint4*)(Wh + (size_t)n0 * 640);
        uint4* d = (uint4*)w_lds;
        for (int i = tid; i < TILE * 160; i += 640) d[i] = s[i];
    }
    {   // x slab (pre-packed, transposed), coalesced uint4
        const uint4* s = (const uint4*)(Xh + (size_t)n0 * 512);
        uint4* d = (uint4*)x_lds;
        for (int i = tid; i < TILE * 128; i += 640) d[i] = s[i];
    }

    float vr0[L_], vr1[L_];
    if (MODE >= 1) {
        #pragma unroll
        for (int l = 0; l < L_; ++l) {
            vr0[l] = va[((size_t)bl * C_ + c) * L_ + l];
            vr1[l] = va[((size_t)(bl + 64) * C_ + c) * L_ + l];
        }
        if (MODE == 2) {
            #pragma unroll
            for (int l = 0; l < L_; ++l) {
                vr0[l] += vb[((size_t)bl * C_ + c) * L_ + l];
                vr1[l] += vb[((size_t)(bl + 64) * C_ + c) * L_ + l];
            }
        }
    }
    __syncthreads();

    float s0[L_], s1[L_];
    #pragma unroll
    for (int l = 0; l < L_; ++l) { s0[l] = 0.f; s1[l] = 0.f; }

    const int coff = __builtin_amdgcn_readfirstlane(c * L_);

    for (int nn = 0; nn < TILE; ++nn) {
        // x: lane-sequential 16B-stride b128 -> conflict-free
        const uint4 xq0 = ((const uint4*)x_lds)[nn * 128 + bl];
        const uint4 xq1 = ((const uint4*)x_lds)[nn * 128 + 64 + bl];
        const unsigned int xa0[4] = {xq0.x, xq0.y, xq0.z, xq0.w};
        const unsigned int xa1[4] = {xq1.x, xq1.y, xq1.z, xq1.w};
        const unsigned int* wb = w_lds + nn * 640 + coff;

        float u0[L_], u1[L_];
        #pragma unroll
        for (int l = 0; l < L_; ++l) { u0[l] = 0.f; u1[l] = 0.f; }
        #pragma unroll
        for (int jp = 0; jp < 4; ++jp) {
            const h2 xh0 = uph(xa0[jp]);
            const h2 xh1 = uph(xa1[jp]);
            #pragma unroll
            for (int q = 0; q < 4; ++q) {
                // wave-uniform broadcast b128 of W (shared by both batch groups)
                const uint4 w4 = *(const uint4*)(wb + jp * 160 + q * 4);
                const unsigned int wa[4] = {w4.x, w4.y, w4.z, w4.w};
                #pragma unroll
                for (int e = 0; e < 4; ++e) {
                    const h2 wh = uph(wa[e]);
                    u0[4 * q + e] = fdot2(xh0, wh, u0[4 * q + e]);
                    u1[4 * q + e] = fdot2(xh1, wh, u1[4 * q + e]);
                }
            }
        }

        if (MODE == 0) {
            #pragma unroll
            for (int l = 0; l < L_; ++l) { s0[l] += u0[l]; s1[l] += u1[l]; }
        } else {
            float t0 = 0.f, t1 = 0.f;
            #pragma unroll
            for (int l = 0; l < L_; ++l) {
                t0 = fmaf(u0[l], vr0[l], t0);
                t1 = fmaf(u1[l], vr1[l], t1);
            }
            const float e0 = __expf(t0);      // |t| small: no max-shift needed
            const float e1 = __expf(t1);
            t_et[c][bl]      = e0;
            t_et[c][bl + 64] = e1;
            __syncthreads();
            if (tid < 128) {                  // designated denominator sum
                float es = 0.f;
                #pragma unroll
                for (int cc = 0; cc < C_; ++cc) es += t_et[cc][tid];
                es_l[tid] = es;
            }
            __syncthreads();                  // also protects t_et for next iter
            const float w0 = e0 * __builtin_amdgcn_rcpf(es_l[bl]);
            const float w1 = e1 * __builtin_amdgcn_rcpf(es_l[bl + 64]);
            #pragma unroll
            for (int l = 0; l < L_; ++l) {
                s0[l] = fmaf(w0, u0[l], s0[l]);
                s1[l] = fmaf(w1, u1[l], s1[l]);
            }
        }
    }

    store16(partials + (((size_t)blockIdx.x * B_ + bl) * C_ + c) * L_, s0);
    store16(partials + (((size_t)blockIdx.x * B_ + bl + 64) * C_ + c) * L_, s1);
}

// Stage A: NCH chunks -> 16 groups; 4 independent accumulators
template<typename PT>
__global__ __launch_bounds__(256)
void reduce_a(const PT* __restrict__ p, float* __restrict__ p2) {
    const int t   = blockIdx.x * 256 + threadIdx.x;   // < RED_G*BCL
    const int idx = t % BCL;
    const int g   = t / BCL;
    constexpr int K = NCH / RED_G;                    // 32
    const PT* base = p + (size_t)g * K * BCL + idx;
    float a0 = 0.f, a1 = 0.f, a2 = 0.f, a3 = 0.f;
    #pragma unroll
    for (int k = 0; k < K; k += 4) {
        a0 += (float)base[(size_t)(k + 0) * BCL];
        a1 += (float)base[(size_t)(k + 1) * BCL];
        a2 += (float)base[(size_t)(k + 2) * BCL];
        a3 += (float)base[(size_t)(k + 3) * BCL];
    }
    p2[t] = (a0 + a1) + (a2 + a3);
}

// Stage B: sum 16 groups, bias, squash (16-lane shuffle tree for ||s||^2)
__global__ __launch_bounds__(256)
void reduce_b(const float* __restrict__ p2, const float* __restrict__ biases,
              float* __restrict__ vout, float scale) {
    const int idx = blockIdx.x * 256 + threadIdx.x;   // < BCL
    float a0 = 0.f, a1 = 0.f, a2 = 0.f, a3 = 0.f;
    #pragma unroll
    for (int g = 0; g < RED_G; g += 4) {
        a0 += p2[(size_t)(g + 0) * BCL + idx];
        a1 += p2[(size_t)(g + 1) * BCL + idx];
        a2 += p2[(size_t)(g + 2) * BCL + idx];
        a3 += p2[(size_t)(g + 3) * BCL + idx];
    }
    const float s = ((a0 + a1) + (a2 + a3)) * scale + biases[idx % 160];
    float n2 = s * s;
    #pragma unroll
    for (int o = 8; o; o >>= 1) n2 += __shfl_xor(n2, o, 16);
    const float n = sqrtf(n2);
    const float f = n2 / ((1.f + n2) * (n + 1e-7f));
    vout[idx] = f * s;
}

template<typename PT>
static void run_all(const float* x, const float* W, const float* biases,
                    float* out, char* ws, hipStream_t stream) {
    unsigned int* Wh = (unsigned int*)ws;                       // 11.8 MB
    unsigned int* Xh = Wh + (size_t)N_ * 640;                   //  9.4 MB
    PT* partials     = (PT*)(Xh + (size_t)N_ * 512);            // NCH*BCL*sizeof(PT)
    float* p2        = (float*)(partials + (size_t)NCH * BCL);  // 1.3 MB
    float* v0        = p2 + (size_t)RED_G * BCL;
    float* v1        = v0 + BCL;

    conv_w<<<(N_ * 640) / 256, 256, 0, stream>>>(W, Wh);
    conv_x<<<(N_ * 128) / 256, 256, 0, stream>>>(x, Xh);

    const dim3 pg(NCH), pb(640);
    const dim3 ag((RED_G * BCL) / 256), bg(BCL / 256);

    pass_kernel<0, PT><<<pg, pb, 0, stream>>>(Xh, Wh, nullptr, nullptr, partials);
    reduce_a<PT><<<ag, 256, 0, stream>>>(partials, p2);
    reduce_b<<<bg, 256, 0, stream>>>(p2, biases, v0, 0.1f);

    pass_kernel<1, PT><<<pg, pb, 0, stream>>>(Xh, Wh, v0, nullptr, partials);
    reduce_a<PT><<<ag, 256, 0, stream>>>(partials, p2);
    reduce_b<<<bg, 256, 0, stream>>>(p2, biases, v1, 1.0f);

    pass_kernel<2, PT><<<pg, pb, 0, stream>>>(Xh, Wh, v0, v1, partials);
    reduce_a<PT><<<ag, 256, 0, stream>>>(partials, p2);
    reduce_b<<<bg, 256, 0, stream>>>(p2, biases, out, 1.0f);
}

extern "C" void kernel_launch(void* const* d_in, const int* in_sizes, int n_in,
                              void* d_out, int out_size, void* d_ws, size_t ws_size,
                              hipStream_t stream) {
    const float* x      = (const float*)d_in[0];
    const float* W      = (const float*)d_in[1];
    const float* biases = (const float*)d_in[2];
    // fp32 partials need 64.66 MB of ws; fall back to f16 partials (43.7 MB).
    if (ws_size >= (size_t)64700000)
        run_all<float>(x, W, biases, (float*)d_out, (char*)d_ws, stream);
    else
        run_all<_Float16>(x, W, biases, (float*)d_out, (char*)d_ws, stream);
}